// Round 1
// baseline (378.686 us; speedup 1.0000x reference)
//
#include <hip/hip_runtime.h>
#include <hip/hip_bf16.h>

// N=4, T=8 -> NT=32 batches; C=C2=256; H*W=1024.
// K1 (colsum only): colsum[q] = sum_p exp(sum_c K[c,p]*Q[c,q] / 16)
// K2 (fused):       recompute e[p,q], attn = e/colsum (written to output),
//                   pval[c,q] = sum_p V[c,p]*attn[p,q]  (32x32x16 bf16 MFMA)
// d_out = [ p_val : 32*256*1024 f32 ][ attn : 32*1024*1024 f32 ]
// The raw-e intermediate (134 MB write + 134 MB read) is eliminated; the
// scores GEMM is recomputed in K2 (17 GFLOP ~ cheaper than 268 MB of HBM).

#define NT_BATCH 32
#define CDIM     256
#define HW       1024

using short8 = __attribute__((ext_vector_type(8))) short;   // 8 bf16 (4 VGPRs)
using f32x16 = __attribute__((ext_vector_type(16))) float;  // 32x32 MFMA acc
using f32x4v = __attribute__((ext_vector_type(4))) float;

__device__ __forceinline__ unsigned pk2(float a, float b) {
  float2 t; t.x = a; t.y = b;
  __hip_bfloat162 h = __float22bfloat162_rn(t);   // v_cvt_pk_bf16_f32
  return *reinterpret_cast<unsigned*>(&h);
}
__device__ __forceinline__ void wr64(void* dst, float a, float b, float c, float d) {
  uint2 v; v.x = pk2(a, b); v.y = pk2(c, d);
  *reinterpret_cast<uint2*>(dst) = v;
}
__device__ __forceinline__ void wr128(void* dst, f32x4v p0, f32x4v p1) {
  uint4 v; v.x = pk2(p0[0], p0[1]); v.y = pk2(p0[2], p0[3]);
  v.z = pk2(p1[0], p1[1]); v.w = pk2(p1[2], p1[3]);
  *reinterpret_cast<uint4*>(dst) = v;
}

// ---------------------------------------------------------------------------
// K1: scores -> exp -> column sums ONLY (no e materialization).
// 128x128 tile, BK=32, 4 waves. Accumulation order / roundings identical to
// K2's recompute so colsum is exactly consistent.
// ---------------------------------------------------------------------------
__global__ __launch_bounds__(256) void k1_scores(const float* __restrict__ Kp,
                                                 const float* __restrict__ Qp,
                                                 float* __restrict__ colsum) {
  __shared__ __align__(16) unsigned short As[128][40];  // [p][c]
  __shared__ __align__(16) unsigned short Bs[128][40];  // [q][c]
  __shared__ float csum[128];

  const int nt = blockIdx.y;
  const int pt = blockIdx.x >> 3, qt = blockIdx.x & 7;
  const int p0 = pt * 128, q0 = qt * 128;
  const float* Kb = Kp + (size_t)nt * (CDIM * HW);
  const float* Qb = Qp + (size_t)nt * (CDIM * HW);

  const int t = threadIdx.x, lane = t & 63;
  const int wave = t >> 6, wm = wave >> 1, wn = wave & 1;
  const int l31 = lane & 31, lhi = lane >> 5;

  // swizzled staging map: bijective (pblk 0..31, cblk 0..7) over 256 threads
  const int pblk = ((t & 7) << 2) | ((t >> 3) & 3);
  const int cblk = ((t >> 5) + (t & 7)) & 7;
  const int sp = pblk << 2, sc = cblk << 2;

  if (t < 128) csum[t] = 0.f;

  f32x16 acc[2][2];
  #pragma unroll
  for (int m = 0; m < 2; ++m)
    #pragma unroll
    for (int n = 0; n < 2; ++n)
      #pragma unroll
      for (int r = 0; r < 16; ++r) acc[m][n][r] = 0.f;

  for (int c0 = 0; c0 < CDIM; c0 += 32) {
    f32x4v kv[4], qv[4];
    #pragma unroll
    for (int j = 0; j < 4; ++j) {
      kv[j] = *(const f32x4v*)&Kb[(size_t)(c0 + sc + j) * HW + p0 + sp];
      qv[j] = *(const f32x4v*)&Qb[(size_t)(c0 + sc + j) * HW + q0 + sp];
    }
    __syncthreads();  // previous iteration's fragment reads complete
    #pragma unroll
    for (int i = 0; i < 4; ++i) {
      wr64(&As[sp + i][sc], kv[0][i], kv[1][i], kv[2][i], kv[3][i]);
      wr64(&Bs[sp + i][sc], qv[0][i], qv[1][i], qv[2][i], qv[3][i]);
    }
    __syncthreads();
    #pragma unroll
    for (int ks = 0; ks < 2; ++ks) {
      short8 a[2], b[2];
      #pragma unroll
      for (int m = 0; m < 2; ++m)
        a[m] = *(const short8*)&As[wm * 64 + m * 32 + l31][ks * 16 + lhi * 8];
      #pragma unroll
      for (int n = 0; n < 2; ++n)
        b[n] = *(const short8*)&Bs[wn * 64 + n * 32 + l31][ks * 16 + lhi * 8];
      #pragma unroll
      for (int m = 0; m < 2; ++m)
        #pragma unroll
        for (int n = 0; n < 2; ++n)
          acc[m][n] = __builtin_amdgcn_mfma_f32_32x32x16_bf16(a[m], b[n], acc[m][n], 0, 0, 0);
    }
  }

  // epilogue: e = exp(s/16); per-column partial sums only
  float part[2] = {0.f, 0.f};
  #pragma unroll
  for (int m = 0; m < 2; ++m) {
    #pragma unroll
    for (int n = 0; n < 2; ++n) {
      #pragma unroll
      for (int r = 0; r < 16; ++r) {
        float e = __expf(acc[m][n][r] * 0.0625f);
        part[n] += e;
      }
    }
  }
  #pragma unroll
  for (int n = 0; n < 2; ++n)
    atomicAdd(&csum[wn * 64 + n * 32 + l31], part[n]);
  __syncthreads();
  if (t < 128) atomicAdd(&colsum[(size_t)nt * HW + q0 + t], csum[t]);
}

// ---------------------------------------------------------------------------
// K2: fused scores-recompute + normalize + attn write + PV GEMM.
// One block per (nt, 64-q strip). Q^T resident in LDS; K^T chunk-staged per
// 64-p tile; V staged per 32-p half. LDS ~73 KB -> 2 blocks/CU.
// ---------------------------------------------------------------------------
__global__ __launch_bounds__(256, 2) void k2_fused(const float* __restrict__ Kp,
                                                   const float* __restrict__ Qp,
                                                   const float* __restrict__ Vp,
                                                   const float* __restrict__ colsum,
                                                   float* __restrict__ A_out,
                                                   float* __restrict__ O) {
  __shared__ __align__(16) unsigned short Qs[64][264];  // [q][c]   33792 B
  __shared__ __align__(16) unsigned short As[64][72];   // [p][c64]  9216 B
  __shared__ __align__(16) unsigned short Vs[256][40];  // [c][p32] 20480 B
  __shared__ __align__(16) unsigned short Ps[64][72];   // [q][p64]  9216 B
  __shared__ float inv_s[64];

  // XCD-chunked swizzle: hw-consecutive blocks round-robin XCDs; give each
  // XCD a contiguous chunk of 64 logical blocks (= 4 nt) so the shared K
  // panel of a batch stays in one XCD's L2.
  const int hbid = blockIdx.y * 16 + blockIdx.x;            // 0..511
  const int lbid = ((hbid & 7) << 6) | (hbid >> 3);
  const int nt = lbid >> 4;
  const int q0 = (lbid & 15) << 6;

  const float* Kb = Kp + (size_t)nt * (CDIM * HW);
  const float* Qb = Qp + (size_t)nt * (CDIM * HW);
  const float* Vb = Vp + (size_t)nt * (CDIM * HW);
  float* Ab = A_out + (size_t)nt * (HW * HW);
  float* Ob = O + (size_t)nt * (CDIM * HW);

  const int t = threadIdx.x, lane = t & 63;
  const int wave = t >> 6, wm = wave >> 1, wn = wave & 1;
  const int l31 = lane & 31, lhi = lane >> 5;

  // staging map: bijective (blkA 0..15, blkB 0..15) over 256 threads
  const int blkA = ((t & 3) << 2) | ((t >> 2) & 3);
  const int blkB = ((t >> 4) + (t & 3)) & 15;
  const int sp = blkA << 2;   // 4 rows (p or q)
  const int sc = blkB << 2;   // 4 cols (c)

  if (t < 64) inv_s[t] = 1.f / colsum[(size_t)nt * HW + q0 + t];

  // ---- stage Q^T resident: Qs[q][c] for q0..q0+63, c 0..255
  #pragma unroll
  for (int cc = 0; cc < 4; ++cc) {
    f32x4v qv[4];
    #pragma unroll
    for (int j = 0; j < 4; ++j)
      qv[j] = *(const f32x4v*)&Qb[(size_t)(cc * 64 + sc + j) * HW + q0 + sp];
    #pragma unroll
    for (int i = 0; i < 4; ++i)
      wr64(&Qs[sp + i][cc * 64 + sc], qv[0][i], qv[1][i], qv[2][i], qv[3][i]);
  }
  __syncthreads();
  const float inv = inv_s[wn * 32 + l31];

  f32x16 accv[2][2];   // pval: wave owns c 64-range; n spans 2x32 q
  #pragma unroll
  for (int m = 0; m < 2; ++m)
    #pragma unroll
    for (int n = 0; n < 2; ++n)
      #pragma unroll
      for (int r = 0; r < 16; ++r) accv[m][n][r] = 0.f;

  for (int p0 = 0; p0 < HW; p0 += 64) {
    // -------- scores: s[p,q] over c=0..255, c-chunks of 64 --------
    f32x16 s;
    #pragma unroll
    for (int r = 0; r < 16; ++r) s[r] = 0.f;

    for (int c0 = 0; c0 < CDIM; c0 += 64) {
      f32x4v kv[4];
      #pragma unroll
      for (int j = 0; j < 4; ++j)
        kv[j] = *(const f32x4v*)&Kb[(size_t)(c0 + sc + j) * HW + p0 + sp];
      __syncthreads();  // prior As fragment reads complete
      #pragma unroll
      for (int i = 0; i < 4; ++i)
        wr64(&As[sp + i][sc], kv[0][i], kv[1][i], kv[2][i], kv[3][i]);
      __syncthreads();
      #pragma unroll
      for (int ks = 0; ks < 4; ++ks) {
        short8 a = *(const short8*)&As[wm * 32 + l31][ks * 16 + lhi * 8];
        short8 b = *(const short8*)&Qs[wn * 32 + l31][c0 + ks * 16 + lhi * 8];
        s = __builtin_amdgcn_mfma_f32_32x32x16_bf16(a, b, s, 0, 0, 0);
      }
    }

    // -------- epilogue: e*inv -> attn store + Ps staging --------
    float ev[16];
    #pragma unroll
    for (int r = 0; r < 16; ++r) ev[r] = __expf(s[r] * 0.0625f) * inv;
    const int prow = wm * 32 + (lhi << 2);
    #pragma unroll
    for (int r = 0; r < 16; ++r) {
      int row = prow + (r & 3) + ((r >> 2) << 3);
      Ab[(size_t)(p0 + row) * HW + q0 + wn * 32 + l31] = ev[r];
    }
    #pragma unroll
    for (int rg = 0; rg < 4; ++rg)
      wr64(&Ps[wn * 32 + l31][wm * 32 + (lhi << 2) + (rg << 3)],
           ev[4 * rg], ev[4 * rg + 1], ev[4 * rg + 2], ev[4 * rg + 3]);

    // -------- PV: two 32-p halves, V staged per half --------
    #pragma unroll
    for (int half = 0; half < 2; ++half) {
      const int ph = p0 + half * 32;
      const int vrow0 = t >> 1, pc = (t & 1) << 4;
      f32x4v vv[2][4];
      #pragma unroll
      for (int rr = 0; rr < 2; ++rr)
        #pragma unroll
        for (int g = 0; g < 4; ++g)
          vv[rr][g] = *(const f32x4v*)&Vb[(size_t)((rr << 7) + vrow0) * HW + ph + pc + (g << 2)];
      __syncthreads();  // half0: Ps visible, prev-tile Vs reads done; half1: PV(0) done
      #pragma unroll
      for (int rr = 0; rr < 2; ++rr) {
        wr128(&Vs[(rr << 7) + vrow0][pc], vv[rr][0], vv[rr][1]);
        wr128(&Vs[(rr << 7) + vrow0][pc + 8], vv[rr][2], vv[rr][3]);
      }
      __syncthreads();
      #pragma unroll
      for (int ks = 0; ks < 2; ++ks) {
        short8 b0 = *(const short8*)&Ps[l31][half * 32 + ks * 16 + lhi * 8];
        short8 b1 = *(const short8*)&Ps[32 + l31][half * 32 + ks * 16 + lhi * 8];
        #pragma unroll
        for (int m = 0; m < 2; ++m) {
          short8 a = *(const short8*)&Vs[wave * 64 + m * 32 + l31][ks * 16 + lhi * 8];
          accv[m][0] = __builtin_amdgcn_mfma_f32_32x32x16_bf16(a, b0, accv[m][0], 0, 0, 0);
          accv[m][1] = __builtin_amdgcn_mfma_f32_32x32x16_bf16(a, b1, accv[m][1], 0, 0, 0);
        }
      }
    }
    // next tile's leading __syncthreads() protects Ps/As/Vs overwrites
  }

  // -------- pval epilogue --------
  #pragma unroll
  for (int m = 0; m < 2; ++m) {
    const int cbase = wave * 64 + m * 32 + (lhi << 2);
    #pragma unroll
    for (int n = 0; n < 2; ++n) {
      const int col = q0 + n * 32 + l31;
      #pragma unroll
      for (int r = 0; r < 16; ++r) {
        int c = cbase + (r & 3) + ((r >> 2) << 3);
        Ob[(size_t)c * HW + col] = accv[m][n][r];
      }
    }
  }
}

// ---------------------------------------------------------------------------
extern "C" void kernel_launch(void* const* d_in, const int* in_sizes, int n_in,
                              void* d_out, int out_size, void* d_ws, size_t ws_size,
                              hipStream_t stream) {
  const float* key   = (const float*)d_in[0];
  const float* query = (const float*)d_in[1];
  const float* value = (const float*)d_in[2];
  float* out  = (float*)d_out;
  float* pval = out;
  float* attn = out + (size_t)NT_BATCH * CDIM * HW;
  float* colsum = (float*)d_ws;  // 32*1024 floats

  hipMemsetAsync(colsum, 0, (size_t)NT_BATCH * HW * sizeof(float), stream);
  k1_scores<<<dim3(64, NT_BATCH), 256, 0, stream>>>(key, query, colsum);
  k2_fused<<<dim3(16, NT_BATCH), 256, 0, stream>>>(key, query, value, colsum, attn, pval);
}